// Round 10
// baseline (33.614 us; speedup 1.0000x reference)
//
#include <hip/hip_runtime.h>

// PixelEffectModule: 8-bin intensity histogram over 11x11 windows at stride 8,
// argmax bin, output that bin's mean RGB, upsampled 8x8.
// Input: rgb (1,3,2048,2048) fp32 in [0,255). Output: (1,3,2048,2048) fp32.
//
// R10 = R9 (green: absmax 0.0, WRITE clean 55 MB, 32.5 us) + MLP fix:
//  - full-row load batching: all 12 dwordx4 loads (3 ch x 4 quads) issued
//    before the bin loop, in BOTH passes -> 12 KB in flight per wave
//    (R9's per-quad loop + VGPR=32 allowed only ~2 loads in flight; at
//    900 ns HBM latency each CU needs ~22 KB in flight to reach 6.3 TB/s).
//  - __launch_bounds__(256,6): ~80-VGPR budget so the 48-float batch +
//    nibble cache (~60 live) fits WITHOUT spill (R6-R8 lesson: the 64-reg
//    8-wave target spills and inflates WRITE_SIZE; tripwire = WRITE > 80 MB).
// Everything else identical to R9: parts=8 half-wave skeleton, XCD swizzle,
// packed-u64 counts, nibble cache, argmax, shfl+LDS reduces, row writes.

#define Wd 2048
#define HW (2048 * 2048)

typedef unsigned int u32;
typedef unsigned long long u64;

// correctly-rounded t/3 (Markstein), 3 ops vs ~9-inst div expansion
__device__ __forceinline__ float div3(float t) {
    const float c = 0x1.555556p-2f;  // RN(1/3)
    float q0 = t * c;
    float r  = __builtin_fmaf(q0, -3.0f, t);
    return __builtin_fmaf(r, c, q0);
}

__global__ __launch_bounds__(256, 6)
void pixel_effect_kernel(const float* __restrict__ rgb, float* __restrict__ out) {
    const int w    = threadIdx.x >> 6;         // wave 0..3
    const int half = (threadIdx.x >> 5) & 1;   // half-wave
    const int cl   = threadIdx.x & 31;         // cell within 32-strip
    const int p    = 2 * w + half;             // row-band part 0..7

    // XCD swizzle (grid 2048 = 8*256, bijective): XCD (wgid&7) owns slots
    // [256*xcd, 256*xcd+256) = 32 contiguous cell-rows.
    u32 wgid = blockIdx.x;
    u32 slot = (wgid & 7u) * 256u + (wgid >> 3);
    const int oy  = (int)(slot >> 3);
    const int bx8 = (int)(slot & 7u);
    const int ox  = bx8 * 32 + cl;

    const float* Rp = rgb;
    const float* Gp = rgb + HW;
    const float* Bp = rgb + 2 * HW;

    // slot j maps x = xbase + j. Interior: xbase=8*(ox-1), valid j in [3,13].
    // ox==0: xbase=0, valid j in [0,5]. All 4 quads always in bounds.
    const int xbase = (ox == 0) ? 0 : ox * 8 - 8;
    const u32 vmask = (ox == 0) ? 0x003Fu : 0x3FF8u;
    const int ytop  = oy * 8 - 5;
    const int rs = (p < 3) ? 2 * p : (3 + p);  // first window-row of this part
    const int nr = (p < 3) ? 2 : 1;            // rows: 2,2,2,1,1,1,1,1

    u64 c64 = 0;
    u32 nbl[2], nbh[2];                        // per-row packed bins (4b/px)

    // ---- pass 1: batched row load, bin pixels, counts + nibble cache ----
#pragma unroll
    for (int k = 0; k < 2; ++k) {
        nbl[k] = 0xFFFFFFFFu; nbh[k] = 0xFFFFFFFFu;
        int y = ytop + rs + k;                 // uniform per half-wave
        if (k < nr && y >= 0) {
            int off = y * Wd + xbase;
            float vR[16], vG[16], vB[16];      // 12 loads issued back-to-back
#pragma unroll
            for (int q = 0; q < 4; ++q) {
                *(float4*)(vR + 4 * q) = *(const float4*)(Rp + off + 4 * q);
                *(float4*)(vG + 4 * q) = *(const float4*)(Gp + off + 4 * q);
                *(float4*)(vB + 4 * q) = *(const float4*)(Bp + off + 4 * q);
            }
            u32 bl = 0, bh = 0;
#pragma unroll
            for (int j = 0; j < 14; ++j) {
                float m = div3(vR[j] + vG[j] + vB[j]);
                u32 bin = (u32)(m * 0.03125f);     // trunc(mean/32), exact
                u32 valid = (vmask >> j) & 1u;
                c64 += (u64)valid << (bin << 3);
                u32 binv = valid ? bin : 15u;      // 15 matches no bin
                if (j < 8) bl |= binv << (4 * j);
                else       bh |= binv << (4 * (j - 8));
            }
            nbl[k] = bl; nbh[k] = bh;
        }
    }

    // ---- cross-half reduce (parts 2w, 2w+1), then 4-wave LDS reduce ----
    c64 += __shfl_xor(c64, 32);

    __shared__ u64 sc[4][32];
    if (half == 0) sc[w][cl] = c64;
    __syncthreads();

    u64 tot = sc[0][cl] + sc[1][cl] + sc[2][cl] + sc[3][cl];   // bytes <=121
    u32 lo = (u32)tot, hi = (u32)(tot >> 32);
    u32 best = 0, bc = lo & 0xFFu;
#pragma unroll
    for (int b = 1; b < 8; ++b) {
        u32 cb = ((b < 4 ? lo : hi) >> ((b & 3) * 8)) & 0xFFu;
        bool t = cb > bc;
        bc   = t ? cb : bc;
        best = t ? (u32)b : best;
    }

    // ---- pass 2: batched re-read (L1/L2-hot), sum winning bin via nibbles ----
    float sr = 0.f, sg = 0.f, sb = 0.f;
#pragma unroll
    for (int k = 0; k < 2; ++k) {
        int y = ytop + rs + k;
        if (k < nr && y >= 0) {
            int off = y * Wd + xbase;
            float vR[16], vG[16], vB[16];
#pragma unroll
            for (int q = 0; q < 4; ++q) {
                *(float4*)(vR + 4 * q) = *(const float4*)(Rp + off + 4 * q);
                *(float4*)(vG + 4 * q) = *(const float4*)(Gp + off + 4 * q);
                *(float4*)(vB + 4 * q) = *(const float4*)(Bp + off + 4 * q);
            }
            u32 bl = nbl[k], bh = nbh[k];
#pragma unroll
            for (int j = 0; j < 14; ++j) {
                u32 bin = ((j < 8) ? (bl >> (4 * j))
                                   : (bh >> (4 * (j - 8)))) & 0xFu;
                float hm = (bin == best) ? 1.0f : 0.0f;
                sr = __builtin_fmaf(hm, vR[j], sr);
                sg = __builtin_fmaf(hm, vG[j], sg);
                sb = __builtin_fmaf(hm, vB[j], sb);
            }
        }
    }
    sr += __shfl_xor(sr, 32);
    sg += __shfl_xor(sg, 32);
    sb += __shfl_xor(sb, 32);

    __shared__ float4 ss[4][32];
    if (half == 0) ss[w][cl] = make_float4(sr, sg, sb, 0.f);
    __syncthreads();

    float4 s0 = ss[0][cl], s1 = ss[1][cl], s2 = ss[2][cl], s3 = ss[3][cl];
    float fbc = (float)bc;
    float orv = (s0.x + s1.x + s2.x + s3.x) / fbc;
    float ogv = (s0.y + s1.y + s2.y + s3.y) / fbc;
    float obv = (s0.z + s1.z + s2.z + s3.z) / fbc;

    // ---- write: part p owns row p of the 8x8 block, 2x float4 per channel ----
    size_t base = (size_t)(oy * 8 + p) * Wd + (size_t)(ox * 8);
    float vals[3] = { orv, ogv, obv };
#pragma unroll
    for (int c = 0; c < 3; ++c) {
        float v = vals[c];
        float4 vv = make_float4(v, v, v, v);
        float* o = out + (size_t)c * HW + base;
        ((float4*)o)[0] = vv;
        ((float4*)o)[1] = vv;
    }
}

extern "C" void kernel_launch(void* const* d_in, const int* in_sizes, int n_in,
                              void* d_out, int out_size, void* d_ws, size_t ws_size,
                              hipStream_t stream) {
    const float* rgb = (const float*)d_in[0];
    float* out = (float*)d_out;
    dim3 block(256, 1, 1);                // 4 waves; wave = 32 cells x 2 parts
    dim3 grid(2048, 1, 1);                // 8 strips/cell-row x 256 rows (swizzled)
    hipLaunchKernelGGL(pixel_effect_kernel, grid, block, 0, stream, rgb, out);
}